// Round 9
// baseline (315.405 us; speedup 1.0000x reference)
//
#include <hip/hip_runtime.h>

typedef unsigned short u16;
typedef __attribute__((ext_vector_type(8))) short short8;
typedef __attribute__((ext_vector_type(4))) float f32x4;
typedef __attribute__((ext_vector_type(4))) unsigned uint4v;

#define NTOK 343
#define DIMC 512
#define HEADS_ 16
#define BATCH 128
#define MROWS 43904
#define TBL 117649

#define LOG2E 1.4426950408889634f
#define QSCALE (0.17677669529663687f * LOG2E)  // hd^-0.5 * log2(e), folded into q

__device__ __forceinline__ u16 f2bf(float f) {
  unsigned u = __builtin_bit_cast(unsigned, f);
  unsigned r = (u + 0x7fffu + ((u >> 16) & 1u)) >> 16;
  return (u16)r;
}
__device__ __forceinline__ float bf2f(u16 x) {
  return __builtin_bit_cast(float, ((unsigned)x) << 16);
}
__device__ __forceinline__ unsigned cvtpk(float lo, float hi) {
  unsigned r;
  asm("v_cvt_pk_bf16_f32 %0, %1, %2" : "=v"(r) : "v"(lo), "v"(hi));
  return r;
}

__global__ void cvt_f32_bf16_k(const float* __restrict__ in, u16* __restrict__ out, int n4) {
  int i = blockIdx.x * blockDim.x + threadIdx.x;
  int st = gridDim.x * blockDim.x;
  for (; i < n4; i += st) {
    float4 v = reinterpret_cast<const float4*>(in)[i];
    ushort4 o;
    o.x = f2bf(v.x); o.y = f2bf(v.y); o.z = f2bf(v.z); o.w = f2bf(v.w);
    reinterpret_cast<ushort4*>(out)[i] = o;
  }
}

// biasB[(((h*22 + nt)*22 + tq)*64 + l)*4 + r] = bf16(log2e * bias(h, q=tq*16+(l&15),
//   k=nt*16+(l>>4)*4+r)), or -1e30 when q/k out of range (masks pad cols).
__global__ void bias_pre_k(const float* __restrict__ table, const int* __restrict__ idx,
                           u16* __restrict__ biasB) {
  int t = blockIdx.x * 256 + threadIdx.x;
  if (t >= HEADS_ * 22 * 22 * 64) return;
  int l = t & 63;
  int tq = (t >> 6) % 22;
  int nt = ((t >> 6) / 22) % 22;
  int h = (t >> 6) / 484;
  int q = tq * 16 + (l & 15);
  int k0 = nt * 16 + (l >> 4) * 4;
  ushort4 o;
  u16* oe = (u16*)&o;
#pragma unroll
  for (int r = 0; r < 4; ++r) {
    int k = k0 + r;
    float v = (q < NTOK && k < NTOK) ? (LOG2E * table[idx[q * NTOK + k] * HEADS_ + h]) : -1e30f;
    oe[r] = f2bf(v);
  }
  *reinterpret_cast<ushort4*>(biasB + (size_t)t * 4) = o;
}

#define GLD16(gptr, lptr)                                                        \
  __builtin_amdgcn_global_load_lds(                                              \
      (const __attribute__((address_space(1))) void*)(const void*)(gptr),        \
      (__attribute__((address_space(3))) void*)(void*)(lptr), 16, 0, 0)

// C = A @ B^T (+bias).  B: [N][K] bf16 (K-contiguous).
// EPI 0: A = x fp32 [M][K]; convert fused into reg-staged A (load float4 early,
//        cvt_pk + ds_write after MFMA cluster - T14 split). bf16 out (+bias, QSCALE).
// EPI 1: A = bf16 [M][K], gload_lds staging (R8 path). fp32 out (+bias).
// Both: 128x128 tile, BK=64, 2-phase dbuf LDS, T2 swizzle triple (content layout
// identical across paths: LDS[row][cb] holds global col (cb*16 ^ swz(row)) data).
template <int EPI>
__global__ __launch_bounds__(256) void gemm_bt_k(const void* __restrict__ Av,
                                                 const u16* __restrict__ B,
                                                 const float* __restrict__ bias,
                                                 void* __restrict__ C, int N, int K) {
  const int NBL = N >> 7;
  int nwg = gridDim.x;
  int orig = blockIdx.x;
  int qq = nwg >> 3, rr = nwg & 7;
  int xcd = orig & 7, lid = orig >> 3;
  int bid = (xcd < rr ? xcd * (qq + 1) : rr * (qq + 1) + (xcd - rr) * qq) + lid;
  int mb = bid / NBL, nb = bid % NBL;
  __shared__ __align__(16) u16 As[2][128 * 64];
  __shared__ __align__(16) u16 Bs[2][128 * 64];
  int tid = threadIdx.x;
  int w = tid >> 6, l = tid & 63;
  int wr = w >> 1, wc = w & 1;
  f32x4 acc[4][4];
#pragma unroll
  for (int i = 0; i < 4; i++)
#pragma unroll
    for (int j = 0; j < 4; j++) acc[i][j] = (f32x4){0.f, 0.f, 0.f, 0.f};

  const int l8r = l >> 3, l8c = l & 7;

  float4 fa[4][2];  // in-flight A fp32 (EPI 0)

  // A fp32: issue 8 float4 loads (source col pre-swizzled, element idx = cbs>>1)
#define LDA_F32(kt)                                                                  \
  {                                                                                  \
    _Pragma("unroll") for (int i4 = 0; i4 < 4; ++i4) {                               \
      int rw = w * 32 + i4 * 8 + l8r;                                                \
      int ce = ((l8c * 16) ^ (((rw >> 1) & 7) << 4)) >> 1;                           \
      const float* src = (const float*)Av + (size_t)(mb * 128 + rw) * K + (kt)*64 + ce; \
      fa[i4][0] = *reinterpret_cast<const float4*>(src);                             \
      fa[i4][1] = *reinterpret_cast<const float4*>(src + 4);                         \
    }                                                                                \
  }
  // A fp32: convert + write to LDS (same content layout as gload_lds path)
#define WRA_F32(slot)                                                                \
  {                                                                                  \
    _Pragma("unroll") for (int i4 = 0; i4 < 4; ++i4) {                               \
      int rw = w * 32 + i4 * 8 + l8r;                                                \
      uint4v wv;                                                                     \
      wv.x = cvtpk(fa[i4][0].x, fa[i4][0].y);                                        \
      wv.y = cvtpk(fa[i4][0].z, fa[i4][0].w);                                        \
      wv.z = cvtpk(fa[i4][1].x, fa[i4][1].y);                                        \
      wv.w = cvtpk(fa[i4][1].z, fa[i4][1].w);                                        \
      *reinterpret_cast<uint4v*>(&As[slot][rw * 64 + l8c * 8]) = wv;                 \
    }                                                                                \
  }
  // A bf16 via gload_lds (EPI 1)
#define LDA_BF(kt, slot)                                                             \
  {                                                                                  \
    _Pragma("unroll") for (int i4 = 0; i4 < 4; ++i4) {                               \
      int rw = w * 32 + i4 * 8 + l8r;                                                \
      int cbs = (l8c * 16) ^ (((rw >> 1) & 7) << 4);                                 \
      GLD16((const u16*)Av + (size_t)(mb * 128 + rw) * K + (kt)*64 + (cbs >> 1),     \
            As[slot] + w * 32 * 64 + i4 * 512 + l * 8);                              \
    }                                                                                \
  }
#define LDB_BF(kt, slot)                                                             \
  {                                                                                  \
    _Pragma("unroll") for (int i4 = 0; i4 < 4; ++i4) {                               \
      int rw = w * 32 + i4 * 8 + l8r;                                                \
      int cbs = (l8c * 16) ^ (((rw >> 1) & 7) << 4);                                 \
      GLD16(B + (size_t)(nb * 128 + rw) * K + (kt)*64 + (cbs >> 1),                  \
            Bs[slot] + w * 32 * 64 + i4 * 512 + l * 8);                              \
    }                                                                                \
  }

  int KT = K >> 6;
  // prologue: tile 0
  if (EPI == 0) { LDA_F32(0); } else { LDA_BF(0, 0); }
  LDB_BF(0, 0);
  if (EPI == 0) { WRA_F32(0); }
  __syncthreads();

  for (int kt = 0; kt < KT; ++kt) {
    int cur = kt & 1;
    if (kt + 1 < KT) {  // issue next-tile loads FIRST (hide under MFMA)
      if (EPI == 0) { LDA_F32(kt + 1); } else { LDA_BF(kt + 1, cur ^ 1); }
      LDB_BF(kt + 1, cur ^ 1);
    }
#pragma unroll
    for (int kk = 0; kk < 2; ++kk) {
      short8 af[4], bf[4];
#pragma unroll
      for (int i = 0; i < 4; i++) {
        int off = (wr * 64 + i * 16 + (l & 15)) * 128 + kk * 64 + (l >> 4) * 16;
        off ^= ((off >> 8) & 7) << 4;  // read-side swizzle
        af[i] = *reinterpret_cast<const short8*>((const u16*)As[cur] + (off >> 1));
      }
#pragma unroll
      for (int j = 0; j < 4; j++) {
        int off = (wc * 64 + j * 16 + (l & 15)) * 128 + kk * 64 + (l >> 4) * 16;
        off ^= ((off >> 8) & 7) << 4;
        bf[j] = *reinterpret_cast<const short8*>((const u16*)Bs[cur] + (off >> 1));
      }
#pragma unroll
      for (int i = 0; i < 4; i++)
#pragma unroll
        for (int j = 0; j < 4; j++)
          acc[i][j] = __builtin_amdgcn_mfma_f32_16x16x32_bf16(af[i], bf[j], acc[i][j], 0, 0, 0);
    }
    if (EPI == 0 && kt + 1 < KT) { WRA_F32(cur ^ 1); }  // write-late (slot free since kt-1 barrier)
    __syncthreads();
  }
#undef LDA_F32
#undef WRA_F32
#undef LDA_BF
#undef LDB_BF

  int r0 = mb * 128 + wr * 64 + (l >> 4) * 4;
  int c0 = nb * 128 + wc * 64 + (l & 15);
#pragma unroll
  for (int j = 0; j < 4; j++) {
    int col = c0 + j * 16;
    float bv = bias[col];
    float mul = (EPI == 0 && col < 512) ? QSCALE : 1.0f;
#pragma unroll
    for (int i = 0; i < 4; i++) {
      int row = r0 + i * 16;
      if (EPI == 0) {
        u16* Cp = (u16*)C + (size_t)row * N + col;
#pragma unroll
        for (int r = 0; r < 4; r += 2) {
          unsigned pk = cvtpk((acc[i][j][r] + bv) * mul, (acc[i][j][r + 1] + bv) * mul);
          Cp[(size_t)r * N] = (u16)pk;
          Cp[(size_t)(r + 1) * N] = (u16)(pk >> 16);
        }
      } else {
#pragma unroll
        for (int r = 0; r < 4; r++)
          ((float*)C)[(size_t)(row + r) * N + col] = acc[i][j][r] + bv;
      }
    }
  }
}

// One block per (b,h). LDS 51.8 KB -> 3 blocks/CU. Swapped QK^T (S^T via mfma(K,Q)) with
// fully in-register softmax; P redistributed to PV A-operand via cvt_pk + shfl_xor(16/32);
// straight PV: A = P, B = vT rows.  (unchanged from R8 passing kernel)
__global__ __launch_bounds__(256, 3) void attn_k(const u16* __restrict__ qkv,
                                                 const u16* __restrict__ biasB,
                                                 u16* __restrict__ outA) {
  int p = blockIdx.x;
  int jj = p >> 3;
  int h = 2 * (p & 7) + (jj >> 7);
  int b = jj & 127;
  __shared__ __align__(16) u16 kS[352 * 40];   // 28,160 B (80 B rows, odd*16B)
  __shared__ __align__(16) u16 vT[32 * 370];   // 23,680 B (v transposed [d][tok])
  int tid = threadIdx.x;

  for (int idx = tid; idx < 352 * 4; idx += 256) {
    int row = idx >> 2, seg = idx & 3;
    uint4 vk = {0, 0, 0, 0};
    if (row < NTOK)
      vk = *reinterpret_cast<const uint4*>(qkv + (size_t)(b * NTOK + row) * 1536 + 512 +
                                           h * 32 + seg * 8);
    *reinterpret_cast<uint4*>(kS + row * 40 + seg * 8) = vk;
  }
  for (int idx = tid; idx < NTOK * 4; idx += 256) {
    int row = idx >> 2, seg = idx & 3;
    size_t base = (size_t)(b * NTOK + row) * 1536 + 1024 + h * 32 + seg * 8;
    uint4 vv = *reinterpret_cast<const uint4*>(qkv + base);
    const u16* e = reinterpret_cast<const u16*>(&vv);
#pragma unroll
    for (int t = 0; t < 8; ++t) vT[(seg * 8 + t) * 370 + row] = e[t];
  }
  for (int idx = tid; idx < 32 * 9; idx += 256) vT[(idx / 9) * 370 + NTOK + (idx % 9)] = 0;
  __syncthreads();

  int w = tid >> 6, l = tid & 63;
  const int cl = l & 15, q4 = l >> 4;
  const f32x4 z4 = (f32x4){0.f, 0.f, 0.f, 0.f};
  for (int tq = w; tq < 22; tq += 4) {
    short8 bq = (short8){0, 0, 0, 0, 0, 0, 0, 0};
    int qrow = tq * 16 + cl;
    if (qrow < NTOK)
      bq = *reinterpret_cast<const short8*>(qkv + (size_t)(b * NTOK + qrow) * 1536 + h * 32 +
                                            q4 * 8);
    unsigned pk[22][2];
    float tot = 0.f;
    const u16* bbase = biasB + ((size_t)(h * 22) * 22 + tq) * 256 + l * 4;
#pragma unroll
    for (int nt = 0; nt < 22; ++nt) {
      short8 ak = *reinterpret_cast<const short8*>(kS + (nt * 16 + cl) * 40 + q4 * 8);
      f32x4 s = __builtin_amdgcn_mfma_f32_16x16x32_bf16(ak, bq, z4, 0, 0, 0);
      ushort4 bb = *reinterpret_cast<const ushort4*>(bbase + (size_t)nt * 22 * 256);
      const u16* be = (const u16*)&bb;
      float e0 = __builtin_amdgcn_exp2f(s[0] + bf2f(be[0]));
      float e1 = __builtin_amdgcn_exp2f(s[1] + bf2f(be[1]));
      float e2 = __builtin_amdgcn_exp2f(s[2] + bf2f(be[2]));
      float e3 = __builtin_amdgcn_exp2f(s[3] + bf2f(be[3]));
      tot += (e0 + e1) + (e2 + e3);
      pk[nt][0] = cvtpk(e0, e1);
      pk[nt][1] = cvtpk(e2, e3);
    }
    tot += __builtin_bit_cast(float, __shfl_xor(__builtin_bit_cast(int, tot), 16));
    tot += __builtin_bit_cast(float, __shfl_xor(__builtin_bit_cast(int, tot), 32));
    float inv = 1.0f / tot;
    float ir[4];
#pragma unroll
    for (int r = 0; r < 4; ++r)
      ir[r] = __shfl(inv, q4 * 4 + r);

    f32x4 O0 = z4, O1 = z4;
#pragma unroll
    for (int kt = 0; kt < 11; ++kt) {
      unsigned v16_0 = (q4 & 2) ? pk[2 * kt + 1][0] : pk[2 * kt][0];
      unsigned v16_1 = (q4 & 2) ? pk[2 * kt + 1][1] : pk[2 * kt][1];
      unsigned v32_0 = (q4 & 2) ? pk[2 * kt][0] : pk[2 * kt + 1][0];
      unsigned v32_1 = (q4 & 2) ? pk[2 * kt][1] : pk[2 * kt + 1][1];
      unsigned t1_0 = (unsigned)__shfl_xor((int)v16_0, 16);
      unsigned t1_1 = (unsigned)__shfl_xor((int)v16_1, 16);
      unsigned t2_0 = (unsigned)__shfl_xor((int)v32_0, 32);
      unsigned t2_1 = (unsigned)__shfl_xor((int)v32_1, 32);
      unsigned t3_0 = (unsigned)__shfl_xor((int)t2_0, 16);
      unsigned t3_1 = (unsigned)__shfl_xor((int)t2_1, 16);
      unsigned f0 = (q4 & 1) ? ((q4 & 2) ? t1_0 : t3_0) : ((q4 & 2) ? t2_0 : v16_0);
      unsigned f1 = (q4 & 1) ? ((q4 & 2) ? t1_1 : t3_1) : ((q4 & 2) ? t2_1 : v16_1);
      unsigned s0 = (q4 & 1) ? ((q4 & 2) ? v16_0 : t2_0) : ((q4 & 2) ? t3_0 : t1_0);
      unsigned s1 = (q4 & 1) ? ((q4 & 2) ? v16_1 : t2_1) : ((q4 & 2) ? t3_1 : t1_1);
      uint4v ap = (uint4v){f0, f1, s0, s1};
      short8 bv0 = *reinterpret_cast<const short8*>(vT + cl * 370 + kt * 32 + q4 * 8);
      short8 bv1 = *reinterpret_cast<const short8*>(vT + (16 + cl) * 370 + kt * 32 + q4 * 8);
      O0 = __builtin_amdgcn_mfma_f32_16x16x32_bf16(__builtin_bit_cast(short8, ap), bv0, O0,
                                                   0, 0, 0);
      O1 = __builtin_amdgcn_mfma_f32_16x16x32_bf16(__builtin_bit_cast(short8, ap), bv1, O1,
                                                   0, 0, 0);
    }
#pragma unroll
    for (int r = 0; r < 4; ++r) {
      int qr2 = tq * 16 + q4 * 4 + r;
      if (qr2 < NTOK) {
        unsigned pko = cvtpk(O0[r] * ir[r], O1[r] * ir[r]);
        u16* op = outA + (size_t)(b * NTOK + qr2) * 512 + h * 32 + cl;
        op[0] = (u16)pko;
        op[16] = (u16)(pko >> 16);
      }
    }
  }
}

extern "C" void kernel_launch(void* const* d_in, const int* in_sizes, int n_in,
                              void* d_out, int out_size, void* d_ws, size_t ws_size,
                              hipStream_t stream) {
  const float* x      = (const float*)d_in[0];
  // d_in[1] = q_global: unused by reference
  const float* qkv_w  = (const float*)d_in[2];
  const float* qkv_b  = (const float*)d_in[3];
  const float* table  = (const float*)d_in[4];
  const float* proj_w = (const float*)d_in[5];
  const float* proj_b = (const float*)d_in[6];
  const int*   relidx = (const int*)d_in[7];

  char* ws = (char*)d_ws;
  u16*   attnO = (u16*)(ws);                 // 44,957,696 B (attn output, bf16)
  u16*   qw_bf = (u16*)(ws + 44957696);      //  1,572,864 B
  u16*   pw_bf = (u16*)(ws + 46530560);      //    524,288 B
  u16*   qkv_o = (u16*)(ws + 47054848);      // 134,873,088 B
  u16*   biasB = (u16*)(ws + 181927936);     //  3,964,928 B (16*22*22*64*4 u16)

  cvt_f32_bf16_k<<<768, 256, 0, stream>>>(qkv_w, qw_bf, (3 * DIMC * DIMC) / 4);
  cvt_f32_bf16_k<<<256, 256, 0, stream>>>(proj_w, pw_bf, (DIMC * DIMC) / 4);
  bias_pre_k<<<(HEADS_ * 22 * 22 * 64 + 255) / 256, 256, 0, stream>>>(table, relidx, biasB);

  gemm_bt_k<0><<<343 * 12, 256, 0, stream>>>(x, qw_bf, qkv_b, qkv_o, 1536, 512);
  attn_k<<<BATCH * HEADS_, 256, 0, stream>>>(qkv_o, biasB, attnO);
  gemm_bt_k<1><<<343 * 4, 256, 0, stream>>>(attnO, pw_bf, proj_b, d_out, 512, 512);
}

// Round 10
// 263.092 us; speedup vs baseline: 1.1988x; 1.1988x over previous
//
#include <hip/hip_runtime.h>

typedef unsigned short u16;
typedef __attribute__((ext_vector_type(8))) short short8;
typedef __attribute__((ext_vector_type(4))) float f32x4;
typedef __attribute__((ext_vector_type(16))) float f32x16;
typedef __attribute__((ext_vector_type(4))) unsigned uint4v;

#define NTOK 343
#define DIMC 512
#define HEADS_ 16
#define BATCH 128
#define MROWS 43904
#define TBL 117649

#define LOG2E 1.4426950408889634f
#define QSCALE (0.17677669529663687f * LOG2E)  // hd^-0.5 * log2(e), folded into q

__device__ __forceinline__ u16 f2bf(float f) {
  unsigned u = __builtin_bit_cast(unsigned, f);
  unsigned r = (u + 0x7fffu + ((u >> 16) & 1u)) >> 16;
  return (u16)r;
}
__device__ __forceinline__ float bf2f(u16 x) {
  return __builtin_bit_cast(float, ((unsigned)x) << 16);
}
__device__ __forceinline__ unsigned cvtpk(float lo, float hi) {
  unsigned r;
  asm("v_cvt_pk_bf16_f32 %0, %1, %2" : "=v"(r) : "v"(lo), "v"(hi));
  return r;
}

__global__ void cvt_f32_bf16_k(const float* __restrict__ in, u16* __restrict__ out, int n4) {
  int i = blockIdx.x * blockDim.x + threadIdx.x;
  int st = gridDim.x * blockDim.x;
  for (; i < n4; i += st) {
    float4 v = reinterpret_cast<const float4*>(in)[i];
    ushort4 o;
    o.x = f2bf(v.x); o.y = f2bf(v.y); o.z = f2bf(v.z); o.w = f2bf(v.w);
    reinterpret_cast<ushort4*>(out)[i] = o;
  }
}

// 32x32 fragment bias: biasB[((h*11 + nt)*11 + tq)*1024 + l*16 + r] =
//   bf16(log2e * bias(h, q = tq*32 + (l&31), tok = nt*32 + (r&3)+8*(r>>2)+4*(l>>5)))
//   or -1e30 when q/tok out of range (masks pads).
__global__ void bias_pre_k(const float* __restrict__ table, const int* __restrict__ idx,
                           u16* __restrict__ biasB) {
  int t = blockIdx.x * 256 + threadIdx.x;
  if (t >= HEADS_ * 121 * 256) return;  // 495,616
  int r4 = t & 3;
  int l = (t >> 2) & 63;
  int rest = t >> 8;
  int tq = rest % 11;
  int nt = (rest / 11) % 11;
  int h = rest / 121;
  int q = tq * 32 + (l & 31);
  int hi = l >> 5;
  ushort4 o;
  u16* oe = (u16*)&o;
#pragma unroll
  for (int rr = 0; rr < 4; ++rr) {
    int r = r4 * 4 + rr;
    int tok = nt * 32 + (r & 3) + 8 * (r >> 2) + 4 * hi;
    float v = (q < NTOK && tok < NTOK) ? (LOG2E * table[idx[q * NTOK + tok] * HEADS_ + h])
                                       : -1e30f;
    oe[rr] = f2bf(v);
  }
  *reinterpret_cast<ushort4*>(biasB +
                              (size_t)(((h * 11 + nt) * 11 + tq) * 1024 + l * 16 + r4 * 4)) = o;
}

#define GLD16(gptr, lptr)                                                        \
  __builtin_amdgcn_global_load_lds(                                              \
      (const __attribute__((address_space(1))) void*)(const void*)(gptr),        \
      (__attribute__((address_space(3))) void*)(void*)(lptr), 16, 0, 0)

// C = A @ B^T (+bias).  A: [M][K] bf16, B: [N][K] bf16 (K-contiguous).
// 128x128 tile, BK=64, 2-phase double-buffered LDS; T2 swizzle triple (rule 21):
// linear gload_lds dest + source col ^ ((row>>1)&7)<<4 + same XOR on read addr.
// (R8 kernel, verbatim — R9's fused-convert variant reverted.)
template <int EPI>
__global__ __launch_bounds__(256) void gemm_bt_k(const u16* __restrict__ A,
                                                 const u16* __restrict__ B,
                                                 const float* __restrict__ bias,
                                                 void* __restrict__ C, int N, int K) {
  const int NBL = N >> 7;
  int nwg = gridDim.x;
  int orig = blockIdx.x;
  int qq = nwg >> 3, rr = nwg & 7;
  int xcd = orig & 7, lid = orig >> 3;
  int bid = (xcd < rr ? xcd * (qq + 1) : rr * (qq + 1) + (xcd - rr) * qq) + lid;
  int mb = bid / NBL, nb = bid % NBL;
  __shared__ __align__(16) u16 As[2][128 * 64];
  __shared__ __align__(16) u16 Bs[2][128 * 64];
  int tid = threadIdx.x;
  int w = tid >> 6, l = tid & 63;
  int wr = w >> 1, wc = w & 1;
  f32x4 acc[4][4];
#pragma unroll
  for (int i = 0; i < 4; i++)
#pragma unroll
    for (int j = 0; j < 4; j++) acc[i][j] = (f32x4){0.f, 0.f, 0.f, 0.f};

  const int l8r = l >> 3, l8c = l & 7;
  const int woff = (w * 32) * 64;

#define STG2(kt, slot)                                                                    \
  {                                                                                       \
    _Pragma("unroll") for (int i4 = 0; i4 < 4; ++i4) {                                    \
      int rowl = w * 32 + i4 * 8 + l8r;                                                   \
      int cbs = (l8c * 16) ^ (((rowl >> 1) & 7) << 4);                                    \
      GLD16(A + (size_t)(mb * 128 + rowl) * K + (kt)*64 + (cbs >> 1),                     \
            As[slot] + woff + i4 * 512 + l * 8);                                          \
      GLD16(B + (size_t)(nb * 128 + rowl) * K + (kt)*64 + (cbs >> 1),                     \
            Bs[slot] + woff + i4 * 512 + l * 8);                                          \
    }                                                                                     \
  }

  int KT = K >> 6;
  STG2(0, 0);
  __syncthreads();
  for (int kt = 0; kt < KT; ++kt) {
    int cur = kt & 1;
    if (kt + 1 < KT) STG2(kt + 1, cur ^ 1);
#pragma unroll
    for (int kk = 0; kk < 2; ++kk) {
      short8 af[4], bf[4];
#pragma unroll
      for (int i = 0; i < 4; i++) {
        int off = (wr * 64 + i * 16 + (l & 15)) * 128 + kk * 64 + (l >> 4) * 16;
        off ^= ((off >> 8) & 7) << 4;
        af[i] = *reinterpret_cast<const short8*>((const u16*)As[cur] + (off >> 1));
      }
#pragma unroll
      for (int j = 0; j < 4; j++) {
        int off = (wc * 64 + j * 16 + (l & 15)) * 128 + kk * 64 + (l >> 4) * 16;
        off ^= ((off >> 8) & 7) << 4;
        bf[j] = *reinterpret_cast<const short8*>((const u16*)Bs[cur] + (off >> 1));
      }
#pragma unroll
      for (int i = 0; i < 4; i++)
#pragma unroll
        for (int j = 0; j < 4; j++)
          acc[i][j] = __builtin_amdgcn_mfma_f32_16x16x32_bf16(af[i], bf[j], acc[i][j], 0, 0, 0);
    }
    __syncthreads();
  }
#undef STG2

  int r0 = mb * 128 + wr * 64 + (l >> 4) * 4;
  int c0 = nb * 128 + wc * 64 + (l & 15);
#pragma unroll
  for (int j = 0; j < 4; j++) {
    int col = c0 + j * 16;
    float bv = bias[col];
    float mul = (EPI == 0 && col < 512) ? QSCALE : 1.0f;
#pragma unroll
    for (int i = 0; i < 4; i++) {
      int row = r0 + i * 16;
      if (EPI == 0) {
        u16* Cp = (u16*)C + (size_t)row * N + col;
#pragma unroll
        for (int r = 0; r < 4; r += 2) {
          unsigned pk = cvtpk((acc[i][j][r] + bv) * mul, (acc[i][j][r + 1] + bv) * mul);
          Cp[(size_t)r * N] = (u16)pk;
          Cp[(size_t)(r + 1) * N] = (u16)(pk >> 16);
        }
      } else {
#pragma unroll
        for (int r = 0; r < 4; r++)
          ((float*)C)[(size_t)(row + r) * N + col] = acc[i][j][r] + bv;
      }
    }
  }
}

// One block per (b,h). LDS 51.8 KB -> 3 blocks/CU. 32x32x16-MFMA scheme:
// lane identity l&31 is simultaneously QK^T C-col (q), PV A-row (q), PV C-col (d),
// so P is lane-local in q; cross-lane move = xor-32 half exchange only.
// S^T = mfma32(K, Q) (2 k-halves); per nt: bias+exp2 (16), pack (8 cvtpk),
// half-exchange (8 shfl_xor32 + 8 sel), PV = 2 x mfma32. Normalization deferred
// to O epilogue via __shfl(inv, qloc).
__global__ __launch_bounds__(256, 3) void attn_k(const u16* __restrict__ qkv,
                                                 const u16* __restrict__ biasB,
                                                 u16* __restrict__ outA) {
  int p = blockIdx.x;
  int jj = p >> 3;
  int h = 2 * (p & 7) + (jj >> 7);
  int b = jj & 127;
  __shared__ __align__(16) u16 kS[352 * 40];   // rows=tok, 80 B rows (odd*16B)
  __shared__ __align__(16) u16 vT[32 * 370];   // [d][tok]
  int tid = threadIdx.x;

  for (int idx = tid; idx < 352 * 4; idx += 256) {
    int row = idx >> 2, seg = idx & 3;
    uint4 vk = {0, 0, 0, 0};
    if (row < NTOK)
      vk = *reinterpret_cast<const uint4*>(qkv + (size_t)(b * NTOK + row) * 1536 + 512 +
                                           h * 32 + seg * 8);
    *reinterpret_cast<uint4*>(kS + row * 40 + seg * 8) = vk;
  }
  for (int idx = tid; idx < NTOK * 4; idx += 256) {
    int row = idx >> 2, seg = idx & 3;
    size_t base = (size_t)(b * NTOK + row) * 1536 + 1024 + h * 32 + seg * 8;
    uint4 vv = *reinterpret_cast<const uint4*>(qkv + base);
    const u16* e = reinterpret_cast<const u16*>(&vv);
#pragma unroll
    for (int t = 0; t < 8; ++t) vT[(seg * 8 + t) * 370 + row] = e[t];
  }
  for (int idx = tid; idx < 32 * 9; idx += 256) vT[(idx / 9) * 370 + NTOK + (idx % 9)] = 0;
  __syncthreads();

  int w = tid >> 6, l = tid & 63;
  const int d32 = l & 31, hi = l >> 5;
  const bool upHalf = (hi != 0);

  for (int tq = w; tq < 11; tq += 4) {
    int qrow = tq * 32 + d32;
    short8 bq0 = (short8){0, 0, 0, 0, 0, 0, 0, 0};
    short8 bq1 = (short8){0, 0, 0, 0, 0, 0, 0, 0};
    if (qrow < NTOK) {
      const u16* qb = qkv + (size_t)(b * NTOK + qrow) * 1536 + h * 32 + hi * 8;
      bq0 = *reinterpret_cast<const short8*>(qb);
      bq1 = *reinterpret_cast<const short8*>(qb + 16);
    }
    f32x16 O = {0, 0, 0, 0, 0, 0, 0, 0, 0, 0, 0, 0, 0, 0, 0, 0};
    float tot = 0.f;
    const u16* bbase = biasB + ((size_t)(h * 121 + tq)) * 1024 + l * 16;  // + nt*11*1024
    for (int nt = 0; nt < 11; ++nt) {
      const u16* kr = kS + (nt * 32 + d32) * 40 + hi * 8;
      short8 ak0 = *reinterpret_cast<const short8*>(kr);       // dims hi*8..+7
      short8 ak1 = *reinterpret_cast<const short8*>(kr + 16);  // dims 16+hi*8..+7
      f32x16 S = {0, 0, 0, 0, 0, 0, 0, 0, 0, 0, 0, 0, 0, 0, 0, 0};
      S = __builtin_amdgcn_mfma_f32_32x32x16_bf16(ak0, bq0, S, 0, 0, 0);
      S = __builtin_amdgcn_mfma_f32_32x32x16_bf16(ak1, bq1, S, 0, 0, 0);
      const u16* bp = bbase + (size_t)nt * 11 * 1024;
      short8 bb0 = *reinterpret_cast<const short8*>(bp);
      short8 bb1 = *reinterpret_cast<const short8*>(bp + 8);
      float ex[16];
#pragma unroll
      for (int r = 0; r < 16; ++r) {
        u16 bw = (u16)((r < 8) ? bb0[r] : bb1[r - 8]);
        float v = S[r] + bf2f(bw);
        ex[r] = __builtin_amdgcn_exp2f(v);
        tot += ex[r];
      }
      unsigned W[8];
#pragma unroll
      for (int r2 = 0; r2 < 8; ++r2) W[r2] = cvtpk(ex[2 * r2], ex[2 * r2 + 1]);
#pragma unroll
      for (int c = 0; c < 2; ++c) {
        unsigned x0 = W[4 * c + 0], x1 = W[4 * c + 1];
        unsigned y0 = W[4 * c + 2], y1 = W[4 * c + 3];
        unsigned x0s = (unsigned)__shfl_xor((int)x0, 32);
        unsigned x1s = (unsigned)__shfl_xor((int)x1, 32);
        unsigned y0s = (unsigned)__shfl_xor((int)y0, 32);
        unsigned y1s = (unsigned)__shfl_xor((int)y1, 32);
        uint4v ap;
        ap.x = upHalf ? y0s : x0;   // elems 0,1 (from lower-half source)
        ap.y = upHalf ? y1s : x1;   // elems 2,3
        ap.z = upHalf ? y0 : x0s;   // elems 4,5 (from upper-half source)
        ap.w = upHalf ? y1 : x1s;   // elems 6,7
        short8 bv = *reinterpret_cast<const short8*>(vT + d32 * 370 + nt * 32 + c * 16 + hi * 8);
        O = __builtin_amdgcn_mfma_f32_32x32x16_bf16(__builtin_bit_cast(short8, ap), bv, O,
                                                    0, 0, 0);
      }
    }
    tot += __builtin_bit_cast(float, __shfl_xor(__builtin_bit_cast(int, tot), 32));
    float inv = 1.0f / tot;
#pragma unroll
    for (int r = 0; r < 16; ++r) {
      int qloc = (r & 3) + 8 * (r >> 2) + 4 * hi;
      float ir = __shfl(inv, qloc);
      int q = tq * 32 + qloc;
      if (q < NTOK) {
        float ov = O[r] * ir;
        outA[(size_t)(b * NTOK + q) * 512 + h * 32 + d32] = (u16)cvtpk(ov, ov);
      }
    }
  }
}

extern "C" void kernel_launch(void* const* d_in, const int* in_sizes, int n_in,
                              void* d_out, int out_size, void* d_ws, size_t ws_size,
                              hipStream_t stream) {
  const float* x      = (const float*)d_in[0];
  // d_in[1] = q_global: unused by reference
  const float* qkv_w  = (const float*)d_in[2];
  const float* qkv_b  = (const float*)d_in[3];
  const float* table  = (const float*)d_in[4];
  const float* proj_w = (const float*)d_in[5];
  const float* proj_b = (const float*)d_in[6];
  const int*   relidx = (const int*)d_in[7];

  char* ws = (char*)d_ws;
  u16*   x_bf  = (u16*)(ws);                 // 44,957,696 B (x bf16, reused as attn-out)
  u16*   qw_bf = (u16*)(ws + 44957696);      //  1,572,864 B
  u16*   pw_bf = (u16*)(ws + 46530560);      //    524,288 B
  u16*   qkv_o = (u16*)(ws + 47054848);      // 134,873,088 B
  u16*   biasB = (u16*)(ws + 181927936);     //  3,964,928 B (16*11*11*1024 u16)

  cvt_f32_bf16_k<<<2048, 256, 0, stream>>>(x, x_bf, (BATCH * NTOK * DIMC) / 4);
  cvt_f32_bf16_k<<<768, 256, 0, stream>>>(qkv_w, qw_bf, (3 * DIMC * DIMC) / 4);
  cvt_f32_bf16_k<<<256, 256, 0, stream>>>(proj_w, pw_bf, (DIMC * DIMC) / 4);
  bias_pre_k<<<1936, 256, 0, stream>>>(table, relidx, biasB);

  gemm_bt_k<0><<<343 * 12, 256, 0, stream>>>(x_bf, qw_bf, qkv_b, qkv_o, 1536, 512);
  attn_k<<<BATCH * HEADS_, 256, 0, stream>>>(qkv_o, biasB, x_bf);
  gemm_bt_k<1><<<343 * 4, 256, 0, stream>>>(x_bf, pw_bf, proj_b, d_out, 512, 512);
}